// Round 5
// baseline (115.585 us; speedup 1.0000x reference)
//
#include <hip/hip_runtime.h>
#include <hip/hip_bf16.h>

#define BB 4
#define QQ 512
#define MM 8192
#define DD 8
#define EE 512
#define SS 256

#define QG 16               // q rows per fused block
#define MSP 8               // m splits (one per XCD)
#define MSL (MM / MSP)      // 1024
#define NQG (BB * QQ / QG)  // 128 q-groups

using f32x4  = __attribute__((ext_vector_type(4))) float;
using bf16x8 = __attribute__((ext_vector_type(8))) short;

static __device__ __forceinline__ unsigned short f2bf(float f) {
  union { __hip_bfloat16 h; unsigned short u; } v;
  v.h = __float2bfloat16(f);
  return v.u;
}

// ---------------------------------------------------------------------------
// K2: projT[b][s][m] = sum_e W[s][e] * V[b][m][e]; f32 in, bf16 out.
// 128x128 tile, BK=64, 256 thr (4 waves 2x2), 2-phase reg-staged pipeline.
// ---------------------------------------------------------------------------
__global__ __launch_bounds__(256) void k_proj(
    const float* __restrict__ V, const float* __restrict__ W,
    unsigned short* __restrict__ projT)
{
  const int m0 = blockIdx.x * 128;
  const int s0 = blockIdx.y * 128;
  const int b  = blockIdx.z;
  const int t = threadIdx.x, lane = t & 63, wv = t >> 6;
  const int wr = wv >> 1, wc = wv & 1;

  __shared__ short lA[128 * 64];
  __shared__ short lB[128 * 64];

  f32x4 acc[4][4] = {};

  const float* Wp = W + (size_t)s0 * EE;
  const float* Vp = V + (size_t)b * MM * EE + (size_t)m0 * EE;

  const int r0 = t >> 4;          // 0..15
  const int c0 = (t & 15) * 4;    // float col
  const int swz = (r0 & 7) << 3;

  float4 ra[8], rb[8];

#define P_LOADS(K0)                                                        \
  _Pragma("unroll")                                                        \
  for (int j = 0; j < 8; ++j) {                                            \
    const int row = j * 16 + r0;                                           \
    ra[j] = *reinterpret_cast<const float4*>(&Wp[(size_t)row * EE + (K0) + c0]); \
    rb[j] = *reinterpret_cast<const float4*>(&Vp[(size_t)row * EE + (K0) + c0]); \
  }

  P_LOADS(0)

  for (int ki = 0; ki < 8; ++ki) {
    __syncthreads();
#pragma unroll
    for (int j = 0; j < 8; ++j) {
      const int row = j * 16 + r0;
      const int idx = (row * 64 + c0) ^ swz;
      ushort4 da, db;
      da.x = f2bf(ra[j].x); da.y = f2bf(ra[j].y); da.z = f2bf(ra[j].z); da.w = f2bf(ra[j].w);
      db.x = f2bf(rb[j].x); db.y = f2bf(rb[j].y); db.z = f2bf(rb[j].z); db.w = f2bf(rb[j].w);
      *reinterpret_cast<ushort4*>(&lA[idx]) = da;
      *reinterpret_cast<ushort4*>(&lB[idx]) = db;
    }
    if (ki < 7) { P_LOADS((ki + 1) * 64) }   // in flight under MFMA phase
    __syncthreads();

#pragma unroll
    for (int kk = 0; kk < 2; ++kk) {
      const int kofs = kk * 32 + (lane >> 4) * 8;
      const int r15 = lane & 15;
      bf16x8 af[4], bfv[4];
#pragma unroll
      for (int mi = 0; mi < 4; ++mi) {
        int row = wr * 64 + mi * 16 + r15;
        af[mi] = *reinterpret_cast<const bf16x8*>(&lA[(row * 64 + kofs) ^ ((row & 7) << 3)]);
      }
#pragma unroll
      for (int ni = 0; ni < 4; ++ni) {
        int row = wc * 64 + ni * 16 + r15;
        bfv[ni] = *reinterpret_cast<const bf16x8*>(&lB[(row * 64 + kofs) ^ ((row & 7) << 3)]);
      }
#pragma unroll
      for (int mi = 0; mi < 4; ++mi)
#pragma unroll
        for (int ni = 0; ni < 4; ++ni)
          acc[mi][ni] = __builtin_amdgcn_mfma_f32_16x16x32_bf16(af[mi], bfv[ni], acc[mi][ni], 0, 0, 0);
    }
  }
#undef P_LOADS

  unsigned short* outp = projT + (size_t)b * SS * MM;
  const int fr = (lane >> 4) * 4;
  const int fc = lane & 15;
#pragma unroll
  for (int mi = 0; mi < 4; ++mi)
#pragma unroll
    for (int ni = 0; ni < 4; ++ni)
#pragma unroll
      for (int r = 0; r < 4; ++r) {
        int s = s0 + wr * 64 + mi * 16 + fr + r;
        int m = m0 + wc * 64 + ni * 16 + fc;
        outp[(size_t)s * MM + m] = f2bf(acc[mi][ni][r]);
      }
}

// ---------------------------------------------------------------------------
// K_FUSED: per (q-group of 16, m-slice of 1024):
//   lavp(q,m) -> row min -> P = exp2(mn - lavp) bf16 in swizzled LDS ->
//   O_part[16x256] = P x projT-slice (MFMA), + per-row (mn, sum) partials.
// wts matrix never materialized. msplit = hw&7 pins slice to one XCD.
// ---------------------------------------------------------------------------
__global__ __launch_bounds__(256, 2) void k_fused(
    const float* __restrict__ loc, const float* __restrict__ locsd,
    const float* __restrict__ mloc, const float* __restrict__ msd,
    const unsigned short* __restrict__ projT,
    float* __restrict__ opart, float* __restrict__ mn_g,
    float* __restrict__ sum_g)
{
  __shared__ float la_s[8 * MSL];            // 32 KB (one 8-row sub-tile)
  __shared__ unsigned short p_s[QG * MSL];   // 32 KB, XOR-swizzled
  __shared__ float lx_s[QG][DD], ls2_s[QG][DD];
  __shared__ float red[QG][4];

  const int hw = blockIdx.x;
  const int ms = hw & 7;            // m-split == XCD
  const int qg = hw >> 3;           // 0..127
  const int b  = qg >> 5;
  const int q0 = (qg & 31) * QG;    // q base within batch
  const int t = threadIdx.x, lane = t & 63, wv = t >> 6;

  // stage q params (128 threads)
  if (t < QG * DD) {
    const int qq = t >> 3, d = t & 7;
    const int base = (b * QQ + q0 + qq) * DD + d;
    lx_s[qq][d] = loc[base];
    float s = locsd[base];
    ls2_s[qq][d] = __builtin_fmaf(s, s, 1e-8f);
  }

  // m-data into registers: m = ms*MSL + c*512 + 2t + p
  const float4* ml4 = reinterpret_cast<const float4*>(mloc + (size_t)b * MM * DD);
  const float4* ms4 = reinterpret_cast<const float4*>(msd  + (size_t)b * MM * DD);
  float mlv[2][2][DD], ms2[2][2][DD];
#pragma unroll
  for (int c = 0; c < 2; ++c)
#pragma unroll
    for (int p = 0; p < 2; ++p) {
      const int m = ms * MSL + c * 512 + 2 * t + p;
      float4 a0 = ml4[2 * m], a1 = ml4[2 * m + 1];
      float4 s0 = ms4[2 * m], s1 = ms4[2 * m + 1];
      mlv[c][p][0] = a0.x; mlv[c][p][1] = a0.y; mlv[c][p][2] = a0.z; mlv[c][p][3] = a0.w;
      mlv[c][p][4] = a1.x; mlv[c][p][5] = a1.y; mlv[c][p][6] = a1.z; mlv[c][p][7] = a1.w;
      ms2[c][p][0] = s0.x * s0.x; ms2[c][p][1] = s0.y * s0.y;
      ms2[c][p][2] = s0.z * s0.z; ms2[c][p][3] = s0.w * s0.w;
      ms2[c][p][4] = s1.x * s1.x; ms2[c][p][5] = s1.y * s1.y;
      ms2[c][p][6] = s1.z * s1.z; ms2[c][p][7] = s1.w * s1.w;
    }
  __syncthreads();

  float rs[QG];
#pragma unroll
  for (int q = 0; q < QG; ++q) rs[q] = 0.f;

#pragma unroll
  for (int sub = 0; sub < 2; ++sub) {
    float mn8[8];
    // ---- affinity pass (lavp = 0.5*log2e*ssum + log2(prod v)) ----
#pragma unroll
    for (int q8 = 0; q8 < 8; ++q8) {
      const int q = sub * 8 + q8;
      float lxq[DD], lsq[DD];
#pragma unroll
      for (int d = 0; d < DD; d += 4) {
        float4 v1 = *reinterpret_cast<const float4*>(&lx_s[q][d]);
        lxq[d] = v1.x; lxq[d + 1] = v1.y; lxq[d + 2] = v1.z; lxq[d + 3] = v1.w;
        float4 v2 = *reinterpret_cast<const float4*>(&ls2_s[q][d]);
        lsq[d] = v2.x; lsq[d + 1] = v2.y; lsq[d + 2] = v2.z; lsq[d + 3] = v2.w;
      }
      float mnq = 3.4e38f;
#pragma unroll
      for (int c = 0; c < 2; ++c) {
        float la2[2];
#pragma unroll
        for (int p = 0; p < 2; ++p) {
          float ssum = 0.f, pr = 1.f;
#pragma unroll
          for (int d = 0; d < DD; ++d) {
            float v  = lsq[d] + ms2[c][p][d];
            float r  = __builtin_amdgcn_rcpf(v);
            float dl = lxq[d] - mlv[c][p][d];
            float d2 = dl * dl;
            float tt = d2 * r;
            ssum = __builtin_fmaf(tt, tt, ssum);
            pr *= v;
          }
          la2[p] = __builtin_fmaf(ssum, 0.72134752f, __builtin_amdgcn_logf(pr));
          mnq = fminf(mnq, la2[p]);
        }
        float2 wr2; wr2.x = la2[0]; wr2.y = la2[1];
        *reinterpret_cast<float2*>(&la_s[q8 * MSL + c * 512 + 2 * t]) = wr2;
      }
      mn8[q8] = mnq;
    }
    // ---- block-wide row min ----
#pragma unroll
    for (int q8 = 0; q8 < 8; ++q8) {
      float v = mn8[q8];
#pragma unroll
      for (int off = 32; off; off >>= 1) v = fminf(v, __shfl_xor(v, off, 64));
      if (lane == 0) red[q8][wv] = v;
    }
    __syncthreads();
    float mnb[8];
#pragma unroll
    for (int q8 = 0; q8 < 8; ++q8) {
      mnb[q8] = fminf(fminf(red[q8][0], red[q8][1]), fminf(red[q8][2], red[q8][3]));
      if (t == q8)
        mn_g[((size_t)qg * MSP + ms) * QG + sub * 8 + q8] = mnb[q8];
    }
    __syncthreads();
    // ---- exp pass: P = exp2(mn - lavp), bf16 pairs into swizzled LDS ----
#pragma unroll
    for (int q8 = 0; q8 < 8; ++q8) {
      const int q = sub * 8 + q8;
      const int swz = (q & 7) << 4;
#pragma unroll
      for (int c = 0; c < 2; ++c) {
        float2 la2 = *reinterpret_cast<const float2*>(&la_s[q8 * MSL + c * 512 + 2 * t]);
        float e0 = __builtin_amdgcn_exp2f(mnb[q8] - la2.x);
        float e1 = __builtin_amdgcn_exp2f(mnb[q8] - la2.y);
        rs[q] += e0 + e1;
        unsigned int pk = (unsigned int)f2bf(e0) | ((unsigned int)f2bf(e1) << 16);
        *reinterpret_cast<unsigned int*>(
            (char*)p_s + (((q * MSL + c * 512 + 2 * t) * 2) ^ swz)) = pk;
      }
    }
  }

  // ---- row sums ----
  __syncthreads();   // also orders all P writes before MFMA reads
#pragma unroll
  for (int q = 0; q < QG; ++q) {
    float v = rs[q];
#pragma unroll
    for (int off = 32; off; off >>= 1) v += __shfl_xor(v, off, 64);
    if (lane == 0) red[q][wv] = v;
  }
  __syncthreads();
#pragma unroll
  for (int q = 0; q < QG; ++q)
    if (t == q)
      sum_g[((size_t)qg * MSP + ms) * QG + q] = red[q][0] + red[q][1] + red[q][2] + red[q][3];

  // ---- MFMA: O = P(16 x 1024) x projT-slice(1024 x 256), wave owns 64 s ----
  const unsigned short* pTb = projT + (size_t)b * SS * MM + (size_t)ms * MSL;
  const int s0w = wv * 64;
  const int qf = lane & 15;           // A row / B row-within-16
  const int kf = (lane >> 4) * 8;     // k offset within 32-chunk
  const int aswz = (qf & 7) << 4;
  f32x4 acc[4] = {};

#define LDA(CH) (*reinterpret_cast<const bf16x8*>( \
    (const char*)p_s + (((qf * MSL + (CH) * 32 + kf) * 2) ^ aswz)))
#define LOADB(U, CH)                                                        \
  _Pragma("unroll")                                                         \
  for (int ni = 0; ni < 4; ++ni)                                            \
    U[ni] = *reinterpret_cast<const uint4*>(                                \
        pTb + (size_t)(s0w + ni * 16 + qf) * MM + (CH) * 32 + kf);

  uint4 u0[4], u1[4];
  bf16x8 a0, a1;
  LOADB(u0, 0) a0 = LDA(0);
#pragma unroll 2
  for (int ch = 0; ch < 32; ch += 2) {
    LOADB(u1, ch + 1) a1 = LDA(ch + 1);
#pragma unroll
    for (int ni = 0; ni < 4; ++ni)
      acc[ni] = __builtin_amdgcn_mfma_f32_16x16x32_bf16(
          a0, *reinterpret_cast<const bf16x8*>(&u0[ni]), acc[ni], 0, 0, 0);
    if (ch + 2 < 32) { LOADB(u0, ch + 2) a0 = LDA(ch + 2); }
#pragma unroll
    for (int ni = 0; ni < 4; ++ni)
      acc[ni] = __builtin_amdgcn_mfma_f32_16x16x32_bf16(
          a1, *reinterpret_cast<const bf16x8*>(&u1[ni]), acc[ni], 0, 0, 0);
  }
#undef LDA
#undef LOADB

  // ---- partial O epilogue: [qg][ms][16][256] f32 ----
  float* op = opart + ((size_t)qg * MSP + ms) * (QG * SS);
#pragma unroll
  for (int ni = 0; ni < 4; ++ni)
#pragma unroll
    for (int r = 0; r < 4; ++r) {
      const int q = (lane >> 4) * 4 + r;
      const int s = s0w + ni * 16 + qf;
      op[q * SS + s] = acc[ni][r];
    }
}

// ---------------------------------------------------------------------------
// K_MERGE: out[row][s] = sum_i O_i[s]*scale_i / sum_i sum_i*scale_i,
//          scale_i = exp2(gmn - mn_i). One wave per q-row.
// ---------------------------------------------------------------------------
__global__ __launch_bounds__(256) void k_merge(
    const float* __restrict__ opart, const float* __restrict__ mn_g,
    const float* __restrict__ sum_g, float* __restrict__ out)
{
  const int row = blockIdx.x * 4 + (threadIdx.x >> 6);   // 0..2047
  const int lane = threadIdx.x & 63;
  const int qg = row >> 4, q = row & 15;

  const float* mnp = mn_g  + (size_t)qg * MSP * QG + q;
  const float* smp = sum_g + (size_t)qg * MSP * QG + q;
  float mns[MSP], gmn = 3.4e38f;
#pragma unroll
  for (int i = 0; i < MSP; ++i) { mns[i] = mnp[i * QG]; gmn = fminf(gmn, mns[i]); }
  float gsum = 0.f, sc[MSP];
#pragma unroll
  for (int i = 0; i < MSP; ++i) {
    sc[i] = __builtin_amdgcn_exp2f(gmn - mns[i]);
    gsum = __builtin_fmaf(smp[i * QG], sc[i], gsum);
  }
  float o[4] = {0.f, 0.f, 0.f, 0.f};
  const float* ob = opart + (size_t)qg * MSP * (QG * SS) + q * SS;
#pragma unroll
  for (int i = 0; i < MSP; ++i)
#pragma unroll
    for (int j = 0; j < 4; ++j)
      o[j] = __builtin_fmaf(ob[(size_t)i * (QG * SS) + j * 64 + lane], sc[i], o[j]);
  const float inv = 1.0f / gsum;
  float* orow = out + (size_t)row * SS;
#pragma unroll
  for (int j = 0; j < 4; ++j) orow[j * 64 + lane] = o[j] * inv;
}

// ---------------------------------------------------------------------------

extern "C" void kernel_launch(void* const* d_in, const int* in_sizes, int n_in,
                              void* d_out, int out_size, void* d_ws, size_t ws_size,
                              hipStream_t stream) {
  const float* loc    = (const float*)d_in[0];
  const float* locsd  = (const float*)d_in[1];
  const float* mloc   = (const float*)d_in[2];
  const float* msd    = (const float*)d_in[3];
  const float* msense = (const float*)d_in[4];
  const float* wread  = (const float*)d_in[5];
  float* out = (float*)d_out;

  const size_t proj_bytes  = (size_t)BB * SS * MM * 2;            // 16.8 MB
  const size_t opart_bytes = (size_t)NQG * MSP * QG * SS * 4;     // 16.8 MB
  const size_t mn_bytes    = (size_t)NQG * MSP * QG * 4;          // 64 KB
  if (ws_size < proj_bytes + opart_bytes + 2 * mn_bytes) return;

  unsigned short* projT = (unsigned short*)d_ws;
  float* opart = (float*)((char*)d_ws + proj_bytes);
  float* mn_g  = (float*)((char*)d_ws + proj_bytes + opart_bytes);
  float* sum_g = (float*)((char*)d_ws + proj_bytes + opart_bytes + mn_bytes);

  hipLaunchKernelGGL(k_proj, dim3(MM / 128, SS / 128, BB), dim3(256), 0, stream,
                     msense, wread, projT);
  hipLaunchKernelGGL(k_fused, dim3(NQG * MSP), dim3(256), 0, stream,
                     loc, locsd, mloc, msd, projT, opart, mn_g, sum_g);
  hipLaunchKernelGGL(k_merge, dim3(BB * QQ / 4), dim3(256), 0, stream,
                     opart, mn_g, sum_g, out);
}

// Round 6
// 111.105 us; speedup vs baseline: 1.0403x; 1.0403x over previous
//
#include <hip/hip_runtime.h>
#include <hip/hip_bf16.h>

#define BB 4
#define QQ 512
#define MM 8192
#define DD 8
#define EE 512
#define SS 256

#define QG 16               // q rows per fused block
#define MSP 8               // m splits (one per XCD)
#define MSL (MM / MSP)      // 1024
#define NQG (BB * QQ / QG)  // 128 q-groups

using f32x4  = __attribute__((ext_vector_type(4))) float;
using bf16x8 = __attribute__((ext_vector_type(8))) short;

static __device__ __forceinline__ unsigned short f2bf(float f) {
  union { __hip_bfloat16 h; unsigned short u; } v;
  v.h = __float2bfloat16(f);
  return v.u;
}

// ---------------------------------------------------------------------------
// K2: projT[b][s][m] = sum_e W[s][e] * V[b][m][e]; f32 in, bf16 out.
// 128x128 tile, BK=64, 256 thr (4 waves 2x2), 2-phase reg-staged pipeline.
// ---------------------------------------------------------------------------
__global__ __launch_bounds__(256) void k_proj(
    const float* __restrict__ V, const float* __restrict__ W,
    unsigned short* __restrict__ projT)
{
  const int m0 = blockIdx.x * 128;
  const int s0 = blockIdx.y * 128;
  const int b  = blockIdx.z;
  const int t = threadIdx.x, lane = t & 63, wv = t >> 6;
  const int wr = wv >> 1, wc = wv & 1;

  __shared__ short lA[128 * 64];
  __shared__ short lB[128 * 64];

  f32x4 acc[4][4] = {};

  const float* Wp = W + (size_t)s0 * EE;
  const float* Vp = V + (size_t)b * MM * EE + (size_t)m0 * EE;

  const int r0 = t >> 4;          // 0..15
  const int c0 = (t & 15) * 4;    // float col
  const int swz = (r0 & 7) << 3;

  float4 ra[8], rb[8];

#define P_LOADS(K0)                                                        \
  _Pragma("unroll")                                                        \
  for (int j = 0; j < 8; ++j) {                                            \
    const int row = j * 16 + r0;                                           \
    ra[j] = *reinterpret_cast<const float4*>(&Wp[(size_t)row * EE + (K0) + c0]); \
    rb[j] = *reinterpret_cast<const float4*>(&Vp[(size_t)row * EE + (K0) + c0]); \
  }

  P_LOADS(0)

  for (int ki = 0; ki < 8; ++ki) {
    __syncthreads();
#pragma unroll
    for (int j = 0; j < 8; ++j) {
      const int row = j * 16 + r0;
      const int idx = (row * 64 + c0) ^ swz;
      ushort4 da, db;
      da.x = f2bf(ra[j].x); da.y = f2bf(ra[j].y); da.z = f2bf(ra[j].z); da.w = f2bf(ra[j].w);
      db.x = f2bf(rb[j].x); db.y = f2bf(rb[j].y); db.z = f2bf(rb[j].z); db.w = f2bf(rb[j].w);
      *reinterpret_cast<ushort4*>(&lA[idx]) = da;
      *reinterpret_cast<ushort4*>(&lB[idx]) = db;
    }
    if (ki < 7) { P_LOADS((ki + 1) * 64) }   // in flight under MFMA phase
    __syncthreads();

#pragma unroll
    for (int kk = 0; kk < 2; ++kk) {
      const int kofs = kk * 32 + (lane >> 4) * 8;
      const int r15 = lane & 15;
      bf16x8 af[4], bfv[4];
#pragma unroll
      for (int mi = 0; mi < 4; ++mi) {
        int row = wr * 64 + mi * 16 + r15;
        af[mi] = *reinterpret_cast<const bf16x8*>(&lA[(row * 64 + kofs) ^ ((row & 7) << 3)]);
      }
#pragma unroll
      for (int ni = 0; ni < 4; ++ni) {
        int row = wc * 64 + ni * 16 + r15;
        bfv[ni] = *reinterpret_cast<const bf16x8*>(&lB[(row * 64 + kofs) ^ ((row & 7) << 3)]);
      }
#pragma unroll
      for (int mi = 0; mi < 4; ++mi)
#pragma unroll
        for (int ni = 0; ni < 4; ++ni)
          acc[mi][ni] = __builtin_amdgcn_mfma_f32_16x16x32_bf16(af[mi], bfv[ni], acc[mi][ni], 0, 0, 0);
    }
  }
#undef P_LOADS

  unsigned short* outp = projT + (size_t)b * SS * MM;
  const int fr = (lane >> 4) * 4;
  const int fc = lane & 15;
#pragma unroll
  for (int mi = 0; mi < 4; ++mi)
#pragma unroll
    for (int ni = 0; ni < 4; ++ni)
#pragma unroll
      for (int r = 0; r < 4; ++r) {
        int s = s0 + wr * 64 + mi * 16 + fr + r;
        int m = m0 + wc * 64 + ni * 16 + fc;
        outp[(size_t)s * MM + m] = f2bf(acc[mi][ni][r]);
      }
}

// ---------------------------------------------------------------------------
// K_FUSED v2: 512 threads (8 waves), la kept in REGISTERS (no la_s LDS),
// LDS ~34KB -> 16 waves/CU. Per thread: 2 m's.
//   lavp(q,m) -> row min -> P = exp2(mn - lavp) bf16 swizzled LDS ->
//   O_part[16x256] = P x projT-slice (MFMA), + per-row (mn, sum) partials.
// ---------------------------------------------------------------------------
__global__ __launch_bounds__(512, 4) void k_fused(
    const float* __restrict__ loc, const float* __restrict__ locsd,
    const float* __restrict__ mloc, const float* __restrict__ msd,
    const unsigned short* __restrict__ projT,
    float* __restrict__ opart, float* __restrict__ mn_g,
    float* __restrict__ sum_g)
{
  __shared__ unsigned short p_s[QG * MSL];   // 32 KB, XOR-swizzled
  __shared__ float lx_s[QG][DD], ls2_s[QG][DD];
  __shared__ float redmin[QG][8];
  __shared__ float redsum[QG][8];

  const int hw = blockIdx.x;
  const int ms = hw & 7;            // m-split == XCD
  const int qg = hw >> 3;           // 0..127
  const int b  = qg >> 5;
  const int q0 = (qg & 31) * QG;    // q base within batch
  const int t = threadIdx.x, lane = t & 63, wv = t >> 6;  // wv 0..7

  // stage q params (128 threads)
  if (t < QG * DD) {
    const int qq = t >> 3, d = t & 7;
    const int base = (b * QQ + q0 + qq) * DD + d;
    lx_s[qq][d] = loc[base];
    float s = locsd[base];
    ls2_s[qq][d] = __builtin_fmaf(s, s, 1e-8f);
  }

  // m-data into registers: m = ms*MSL + 2t + p   (2 m per thread)
  const float4* ml4 = reinterpret_cast<const float4*>(mloc + (size_t)b * MM * DD);
  const float4* ms4 = reinterpret_cast<const float4*>(msd  + (size_t)b * MM * DD);
  float mlv[2][DD], ms2[2][DD];
#pragma unroll
  for (int p = 0; p < 2; ++p) {
    const int m = ms * MSL + 2 * t + p;
    float4 a0 = ml4[2 * m], a1 = ml4[2 * m + 1];
    float4 s0 = ms4[2 * m], s1 = ms4[2 * m + 1];
    mlv[p][0] = a0.x; mlv[p][1] = a0.y; mlv[p][2] = a0.z; mlv[p][3] = a0.w;
    mlv[p][4] = a1.x; mlv[p][5] = a1.y; mlv[p][6] = a1.z; mlv[p][7] = a1.w;
    ms2[p][0] = s0.x * s0.x; ms2[p][1] = s0.y * s0.y;
    ms2[p][2] = s0.z * s0.z; ms2[p][3] = s0.w * s0.w;
    ms2[p][4] = s1.x * s1.x; ms2[p][5] = s1.y * s1.y;
    ms2[p][6] = s1.z * s1.z; ms2[p][7] = s1.w * s1.w;
  }
  __syncthreads();

  const size_t g_base = ((size_t)qg * MSP + ms) * QG;

#pragma unroll
  for (int sub = 0; sub < 2; ++sub) {
    float la_r[8][2];
    // ---- affinity pass (lavp = 0.5*log2e*ssum + log2(prod v)) ----
#pragma unroll
    for (int q8 = 0; q8 < 8; ++q8) {
      const int q = sub * 8 + q8;
      float lxq[DD], lsq[DD];
#pragma unroll
      for (int d = 0; d < DD; d += 4) {
        float4 v1 = *reinterpret_cast<const float4*>(&lx_s[q][d]);
        lxq[d] = v1.x; lxq[d + 1] = v1.y; lxq[d + 2] = v1.z; lxq[d + 3] = v1.w;
        float4 v2 = *reinterpret_cast<const float4*>(&ls2_s[q][d]);
        lsq[d] = v2.x; lsq[d + 1] = v2.y; lsq[d + 2] = v2.z; lsq[d + 3] = v2.w;
      }
      float mnq = 3.4e38f;
#pragma unroll
      for (int p = 0; p < 2; ++p) {
        float ssum = 0.f, pr = 1.f;
#pragma unroll
        for (int d = 0; d < DD; ++d) {
          float v  = lsq[d] + ms2[p][d];
          float r  = __builtin_amdgcn_rcpf(v);
          float dl = lxq[d] - mlv[p][d];
          float d2 = dl * dl;
          float tt = d2 * r;
          ssum = __builtin_fmaf(tt, tt, ssum);
          pr *= v;
        }
        la_r[q8][p] = __builtin_fmaf(ssum, 0.72134752f, __builtin_amdgcn_logf(pr));
        mnq = fminf(mnq, la_r[q8][p]);
      }
      // wave-level min
#pragma unroll
      for (int off = 32; off; off >>= 1) mnq = fminf(mnq, __shfl_xor(mnq, off, 64));
      if (lane == 0) redmin[q][wv] = mnq;
    }
    __syncthreads();
    float mnb[8];
#pragma unroll
    for (int q8 = 0; q8 < 8; ++q8) {
      const int q = sub * 8 + q8;
      float m2 = redmin[q][0];
#pragma unroll
      for (int w = 1; w < 8; ++w) m2 = fminf(m2, redmin[q][w]);
      mnb[q8] = m2;
      if (t == q8) mn_g[g_base + q] = m2;
    }
    // ---- exp pass: P = exp2(mn - lavp), bf16 pairs into swizzled LDS ----
#pragma unroll
    for (int q8 = 0; q8 < 8; ++q8) {
      const int q = sub * 8 + q8;
      const int swz = (q & 7) << 4;
      float e0 = __builtin_amdgcn_exp2f(mnb[q8] - la_r[q8][0]);
      float e1 = __builtin_amdgcn_exp2f(mnb[q8] - la_r[q8][1]);
      unsigned int pk = (unsigned int)f2bf(e0) | ((unsigned int)f2bf(e1) << 16);
      *reinterpret_cast<unsigned int*>(
          (char*)p_s + (((q * MSL + 2 * t) * 2) ^ swz)) = pk;
      float v = e0 + e1;
#pragma unroll
      for (int off = 32; off; off >>= 1) v += __shfl_xor(v, off, 64);
      if (lane == 0) redsum[q][wv] = v;
    }
  }

  __syncthreads();   // orders P writes before MFMA reads; redsum complete
  if (t < QG) {
    float s = 0.f;
#pragma unroll
    for (int w = 0; w < 8; ++w) s += redsum[t][w];
    sum_g[g_base + t] = s;
  }

  // ---- MFMA: O = P(16 x 1024) x projT-slice(1024 x 256), wave owns 32 s ----
  const unsigned short* pTb = projT + (size_t)b * SS * MM + (size_t)ms * MSL;
  const int s0w = wv * 32;
  const int qf = lane & 15;           // A row / B col-within-16
  const int kf = (lane >> 4) * 8;     // k offset within 32-chunk
  const int aswz = (qf & 7) << 4;
  f32x4 acc[2] = {};

#define LDA(CH) (*reinterpret_cast<const bf16x8*>( \
    (const char*)p_s + (((qf * MSL + (CH) * 32 + kf) * 2) ^ aswz)))
#define LOADB(U, CH)                                                        \
  _Pragma("unroll")                                                         \
  for (int ni = 0; ni < 2; ++ni)                                            \
    U[ni] = *reinterpret_cast<const uint4*>(                                \
        pTb + (size_t)(s0w + ni * 16 + qf) * MM + (CH) * 32 + kf);

  uint4 u0[2], u1[2];
  bf16x8 a0, a1;
  LOADB(u0, 0) a0 = LDA(0);
#pragma unroll 2
  for (int ch = 0; ch < 32; ch += 2) {
    LOADB(u1, ch + 1) a1 = LDA(ch + 1);
#pragma unroll
    for (int ni = 0; ni < 2; ++ni)
      acc[ni] = __builtin_amdgcn_mfma_f32_16x16x32_bf16(
          a0, *reinterpret_cast<const bf16x8*>(&u0[ni]), acc[ni], 0, 0, 0);
    if (ch + 2 < 32) { LOADB(u0, ch + 2) a0 = LDA(ch + 2); }
#pragma unroll
    for (int ni = 0; ni < 2; ++ni)
      acc[ni] = __builtin_amdgcn_mfma_f32_16x16x32_bf16(
          a1, *reinterpret_cast<const bf16x8*>(&u1[ni]), acc[ni], 0, 0, 0);
  }
#undef LDA
#undef LOADB

  // ---- partial O epilogue: [qg][ms][16][256] f32 ----
  float* op = opart + g_base * SS;
#pragma unroll
  for (int ni = 0; ni < 2; ++ni)
#pragma unroll
    for (int r = 0; r < 4; ++r) {
      const int q = (lane >> 4) * 4 + r;
      const int s = s0w + ni * 16 + qf;
      op[q * SS + s] = acc[ni][r];
    }
}

// ---------------------------------------------------------------------------
// K_MERGE: out[row][s] = sum_i O_i[s]*scale_i / sum_i sum_i*scale_i,
//          scale_i = exp2(gmn - mn_i). One wave per q-row.
// ---------------------------------------------------------------------------
__global__ __launch_bounds__(256) void k_merge(
    const float* __restrict__ opart, const float* __restrict__ mn_g,
    const float* __restrict__ sum_g, float* __restrict__ out)
{
  const int row = blockIdx.x * 4 + (threadIdx.x >> 6);   // 0..2047
  const int lane = threadIdx.x & 63;
  const int qg = row >> 4, q = row & 15;

  const float* mnp = mn_g  + (size_t)qg * MSP * QG + q;
  const float* smp = sum_g + (size_t)qg * MSP * QG + q;
  float mns[MSP], gmn = 3.4e38f;
#pragma unroll
  for (int i = 0; i < MSP; ++i) { mns[i] = mnp[i * QG]; gmn = fminf(gmn, mns[i]); }
  float gsum = 0.f, sc[MSP];
#pragma unroll
  for (int i = 0; i < MSP; ++i) {
    sc[i] = __builtin_amdgcn_exp2f(gmn - mns[i]);
    gsum = __builtin_fmaf(smp[i * QG], sc[i], gsum);
  }
  float o[4] = {0.f, 0.f, 0.f, 0.f};
  const float* ob = opart + (size_t)qg * MSP * (QG * SS) + q * SS;
#pragma unroll
  for (int i = 0; i < MSP; ++i)
#pragma unroll
    for (int j = 0; j < 4; ++j)
      o[j] = __builtin_fmaf(ob[(size_t)i * (QG * SS) + j * 64 + lane], sc[i], o[j]);
  const float inv = 1.0f / gsum;
  float* orow = out + (size_t)row * SS;
#pragma unroll
  for (int j = 0; j < 4; ++j) orow[j * 64 + lane] = o[j] * inv;
}

// ---------------------------------------------------------------------------

extern "C" void kernel_launch(void* const* d_in, const int* in_sizes, int n_in,
                              void* d_out, int out_size, void* d_ws, size_t ws_size,
                              hipStream_t stream) {
  const float* loc    = (const float*)d_in[0];
  const float* locsd  = (const float*)d_in[1];
  const float* mloc   = (const float*)d_in[2];
  const float* msd    = (const float*)d_in[3];
  const float* msense = (const float*)d_in[4];
  const float* wread  = (const float*)d_in[5];
  float* out = (float*)d_out;

  const size_t proj_bytes  = (size_t)BB * SS * MM * 2;            // 16.8 MB
  const size_t opart_bytes = (size_t)NQG * MSP * QG * SS * 4;     // 16.8 MB
  const size_t mn_bytes    = (size_t)NQG * MSP * QG * 4;          // 64 KB
  if (ws_size < proj_bytes + opart_bytes + 2 * mn_bytes) return;

  unsigned short* projT = (unsigned short*)d_ws;
  float* opart = (float*)((char*)d_ws + proj_bytes);
  float* mn_g  = (float*)((char*)d_ws + proj_bytes + opart_bytes);
  float* sum_g = (float*)((char*)d_ws + proj_bytes + opart_bytes + mn_bytes);

  hipLaunchKernelGGL(k_proj, dim3(MM / 128, SS / 128, BB), dim3(256), 0, stream,
                     msense, wread, projT);
  hipLaunchKernelGGL(k_fused, dim3(NQG * MSP), dim3(512), 0, stream,
                     loc, locsd, mloc, msd, projT, opart, mn_g, sum_g);
  hipLaunchKernelGGL(k_merge, dim3(BB * QQ / 4), dim3(256), 0, stream,
                     opart, mn_g, sum_g, out);
}